// Round 1
// baseline (584.335 us; speedup 1.0000x reference)
//
#include <hip/hip_runtime.h>
#include <hip/hip_bf16.h>

#define N_NODES 50000
#define N_EDGES 800000
#define HID 64
#define HEADS 4
#define CONVS 2
#define CLS 16
#define SLOPE 0.2f
#define SCAN_B 1024

// ---------------- CSR build ----------------

__global__ void hist_kernel(const int* __restrict__ dst, int* __restrict__ deg) {
    int e = blockIdx.x * blockDim.x + threadIdx.x;
    if (e < N_EDGES) atomicAdd(&deg[dst[e]], 1);
}

__global__ void scan1_kernel(const int* __restrict__ deg, int* __restrict__ row_ptr,
                             int* __restrict__ tops) {
    __shared__ int buf[SCAN_B];
    int i = blockIdx.x * SCAN_B + threadIdx.x;
    int v = (i < N_NODES) ? deg[i] : 0;
    buf[threadIdx.x] = v;
    __syncthreads();
    for (int off = 1; off < SCAN_B; off <<= 1) {
        int t = (threadIdx.x >= off) ? buf[threadIdx.x - off] : 0;
        __syncthreads();
        buf[threadIdx.x] += t;
        __syncthreads();
    }
    if (i < N_NODES) row_ptr[i + 1] = buf[threadIdx.x];
    if (threadIdx.x == SCAN_B - 1) tops[blockIdx.x] = buf[threadIdx.x];
}

__global__ void scan2_kernel(int* __restrict__ tops, int nb) {
    if (threadIdx.x == 0 && blockIdx.x == 0) {
        int acc = 0;
        for (int b = 0; b < nb; b++) { int t = tops[b]; tops[b] = acc; acc += t; }
    }
}

__global__ void scan3_kernel(int* __restrict__ row_ptr, const int* __restrict__ tops) {
    int i = blockIdx.x * SCAN_B + threadIdx.x;
    if (i < N_NODES) row_ptr[i + 1] += tops[blockIdx.x];
    if (i == 0 && blockIdx.x == 0) row_ptr[0] = 0;
}

__global__ void scatter_kernel(const int* __restrict__ src, const int* __restrict__ dst,
                               const int* __restrict__ row_ptr, int* __restrict__ cursor,
                               int* __restrict__ col) {
    int e = blockIdx.x * blockDim.x + threadIdx.x;
    if (e < N_EDGES) {
        int d = dst[e];
        int pos = row_ptr[d] + atomicAdd(&cursor[d], 1);
        col[pos] = src[e];
    }
}

// ---------------- per-type projection: h = feat @ W1 + b1, s = rowsum(h) ----------------

__global__ __launch_bounds__(256)
void proj_kernel(const float* __restrict__ feat, const float* __restrict__ W,
                 const float* __restrict__ b, float* __restrict__ h,
                 float* __restrict__ s_out, int rows, int K, int base_row) {
    int lane = threadIdx.x & 63;
    int wid  = threadIdx.x >> 6;
    int r = blockIdx.x * 4 + wid;
    if (r >= rows) return;
    const float* arow = feat + (size_t)r * K;
    float acc = b[lane];
    for (int kk = 0; kk < K; kk += 4) {
        float4 a4 = *reinterpret_cast<const float4*>(arow + kk);
        acc = fmaf(a4.x, W[(kk + 0) * 64 + lane], acc);
        acc = fmaf(a4.y, W[(kk + 1) * 64 + lane], acc);
        acc = fmaf(a4.z, W[(kk + 2) * 64 + lane], acc);
        acc = fmaf(a4.w, W[(kk + 3) * 64 + lane], acc);
    }
    int gr = base_row + r;
    h[(size_t)gr * 64 + lane] = acc;
    float ssum = acc;
    #pragma unroll
    for (int off = 32; off; off >>= 1) ssum += __shfl_xor(ssum, off);
    if (lane == 0) s_out[gr] = ssum;
}

// ---------------- conv 0 (all 4 heads fused; shared input h) ----------------
// wave per dst node; lane = channel.
// e[e,k] = leaky(al_k*s_src + ar_k*s_dst). Monotone in s_src -> segment max at
// endpoint of [s_min, s_max] over incoming edges.

__global__ __launch_bounds__(256)
void conv0_kernel(const float* __restrict__ h, const float* __restrict__ s_h,
                  const float* __restrict__ al, const float* __restrict__ ar,
                  const int* __restrict__ row_ptr, const int* __restrict__ col,
                  float* __restrict__ x1, float* __restrict__ s1) {
    int lane = threadIdx.x & 63;
    int wid  = threadIdx.x >> 6;
    int n = blockIdx.x * 4 + wid;
    if (n >= N_NODES) return;

    float sd = s_h[n];
    int base = row_ptr[n];
    int deg  = row_ptr[n + 1] - base;

    float alk[HEADS], ck[HEADS], mm[HEADS], den[HEADS], num[HEADS];
    #pragma unroll
    for (int hd = 0; hd < HEADS; hd++) {
        alk[hd] = al[(hd * CONVS + 0) * 64 + lane];
        float arv = ar[(hd * CONVS + 0) * 64 + lane];
        ck[hd] = arv * sd;
    }

    // pass A: min/max of neighbor scalars (lane-parallel over edges)
    float smax = -INFINITY, smin = INFINITY;
    for (int j = lane; j < deg; j += 64) {
        float sv = s_h[col[base + j]];
        smax = fmaxf(smax, sv);
        smin = fminf(smin, sv);
    }
    #pragma unroll
    for (int off = 32; off; off >>= 1) {
        smax = fmaxf(smax, __shfl_xor(smax, off));
        smin = fminf(smin, __shfl_xor(smin, off));
    }

    #pragma unroll
    for (int hd = 0; hd < HEADS; hd++) {
        float t1 = fmaf(alk[hd], smax, ck[hd]); t1 = fmaxf(t1, SLOPE * t1);
        float t2 = fmaf(alk[hd], smin, ck[hd]); t2 = fmaxf(t2, SLOPE * t2);
        mm[hd] = fmaxf(t1, t2);
        den[hd] = 0.f; num[hd] = 0.f;
    }

    // pass B: weighted aggregation
    for (int j = 0; j < deg; j++) {
        int srcj = col[base + j];          // wave-uniform broadcast load
        float sv = s_h[srcj];              // broadcast
        float hv = h[(size_t)srcj * 64 + lane]; // coalesced 256B gather
        #pragma unroll
        for (int hd = 0; hd < HEADS; hd++) {
            float t = fmaf(alk[hd], sv, ck[hd]);
            t = fmaxf(t, SLOPE * t);       // leaky_relu(x)=max(x,0.2x)
            float w = __expf(t - mm[hd]);
            den[hd] += w;
            num[hd] = fmaf(hv, w, num[hd]);
        }
    }

    #pragma unroll
    for (int hd = 0; hd < HEADS; hd++) {
        float o = num[hd] / den[hd];
        x1[((size_t)hd * N_NODES + n) * 64 + lane] = o;
        float ss = o;
        #pragma unroll
        for (int off = 32; off; off >>= 1) ss += __shfl_xor(ss, off);
        if (lane == 0) s1[hd * N_NODES + n] = ss;
    }
}

// ---------------- conv 1 + residual + relu + z@W2+b2 + relu@W3+b3 ----------------

__global__ __launch_bounds__(256)
void conv1_fused_kernel(const float* __restrict__ h, const float* __restrict__ x1,
                        const float* __restrict__ s1,
                        const float* __restrict__ al, const float* __restrict__ ar,
                        const int* __restrict__ row_ptr, const int* __restrict__ col,
                        const float* __restrict__ W2, const float* __restrict__ b2,
                        const float* __restrict__ W3, const float* __restrict__ b3,
                        float* __restrict__ out_logits, float* __restrict__ out_encoded) {
    int lane = threadIdx.x & 63;
    int wid  = threadIdx.x >> 6;
    int n = blockIdx.x * 4 + wid;
    if (n >= N_NODES) return;

    int base = row_ptr[n];
    int deg  = row_ptr[n + 1] - base;

    float alk[HEADS], ck[HEADS], mm[HEADS], den[HEADS], num[HEADS];
    #pragma unroll
    for (int hd = 0; hd < HEADS; hd++) {
        float sd = s1[hd * N_NODES + n];
        alk[hd] = al[(hd * CONVS + 1) * 64 + lane];
        float arv = ar[(hd * CONVS + 1) * 64 + lane];
        ck[hd] = arv * sd;
    }

    float smax0 = -INFINITY, smin0 = INFINITY;
    float smax1 = -INFINITY, smin1 = INFINITY;
    float smax2 = -INFINITY, smin2 = INFINITY;
    float smax3 = -INFINITY, smin3 = INFINITY;
    for (int j = lane; j < deg; j += 64) {
        int c = col[base + j];
        float v0 = s1[0 * N_NODES + c];
        float v1 = s1[1 * N_NODES + c];
        float v2 = s1[2 * N_NODES + c];
        float v3 = s1[3 * N_NODES + c];
        smax0 = fmaxf(smax0, v0); smin0 = fminf(smin0, v0);
        smax1 = fmaxf(smax1, v1); smin1 = fminf(smin1, v1);
        smax2 = fmaxf(smax2, v2); smin2 = fminf(smin2, v2);
        smax3 = fmaxf(smax3, v3); smin3 = fminf(smin3, v3);
    }
    #pragma unroll
    for (int off = 32; off; off >>= 1) {
        smax0 = fmaxf(smax0, __shfl_xor(smax0, off)); smin0 = fminf(smin0, __shfl_xor(smin0, off));
        smax1 = fmaxf(smax1, __shfl_xor(smax1, off)); smin1 = fminf(smin1, __shfl_xor(smin1, off));
        smax2 = fmaxf(smax2, __shfl_xor(smax2, off)); smin2 = fminf(smin2, __shfl_xor(smin2, off));
        smax3 = fmaxf(smax3, __shfl_xor(smax3, off)); smin3 = fminf(smin3, __shfl_xor(smin3, off));
    }
    float smaxA[HEADS] = {smax0, smax1, smax2, smax3};
    float sminA[HEADS] = {smin0, smin1, smin2, smin3};
    #pragma unroll
    for (int hd = 0; hd < HEADS; hd++) {
        float t1 = fmaf(alk[hd], smaxA[hd], ck[hd]); t1 = fmaxf(t1, SLOPE * t1);
        float t2 = fmaf(alk[hd], sminA[hd], ck[hd]); t2 = fmaxf(t2, SLOPE * t2);
        mm[hd] = fmaxf(t1, t2);
        den[hd] = 0.f; num[hd] = 0.f;
    }

    for (int j = 0; j < deg; j++) {
        int srcj = col[base + j];
        #pragma unroll
        for (int hd = 0; hd < HEADS; hd++) {
            float sv = s1[hd * N_NODES + srcj];
            float hv = x1[((size_t)hd * N_NODES + srcj) * 64 + lane];
            float t = fmaf(alk[hd], sv, ck[hd]);
            t = fmaxf(t, SLOPE * t);
            float w = __expf(t - mm[hd]);
            den[hd] += w;
            num[hd] = fmaf(hv, w, num[hd]);
        }
    }

    float hres = h[(size_t)n * 64 + lane];
    float z0 = fmaxf(hres + num[0] / den[0], 0.f);
    float z1 = fmaxf(hres + num[1] / den[1], 0.f);
    float z2 = fmaxf(hres + num[2] / den[2], 0.f);
    float z3 = fmaxf(hres + num[3] / den[3], 0.f);

    // encoded[n, lane] = sum_kk z[kk] * W2[kk, lane] + b2[lane]
    float acc = b2[lane];
    const float* w2p = W2 + lane;
    #pragma unroll 4
    for (int q = 0; q < 64; q++) {
        float zv = __shfl(z0, q);
        acc = fmaf(zv, w2p[(0 * 64 + q) * 64], acc);
    }
    #pragma unroll 4
    for (int q = 0; q < 64; q++) {
        float zv = __shfl(z1, q);
        acc = fmaf(zv, w2p[(1 * 64 + q) * 64], acc);
    }
    #pragma unroll 4
    for (int q = 0; q < 64; q++) {
        float zv = __shfl(z2, q);
        acc = fmaf(zv, w2p[(2 * 64 + q) * 64], acc);
    }
    #pragma unroll 4
    for (int q = 0; q < 64; q++) {
        float zv = __shfl(z3, q);
        acc = fmaf(zv, w2p[(3 * 64 + q) * 64], acc);
    }
    out_encoded[(size_t)n * 64 + lane] = acc;

    // logits[n, c] = sum_k relu(enc_k) * W3[k, c] + b3[c]
    float er = fmaxf(acc, 0.f);
    int c16 = lane & 15;
    int k0  = (lane >> 4) * 16;
    float part = 0.f;
    #pragma unroll
    for (int j = 0; j < 16; j++) {
        float ev = __shfl(er, k0 + j);
        part = fmaf(ev, W3[(k0 + j) * CLS + c16], part);
    }
    part += __shfl_xor(part, 16);
    part += __shfl_xor(part, 32);
    if (lane < CLS) out_logits[(size_t)n * CLS + lane] = part + b3[lane];
}

// ---------------- launch ----------------

extern "C" void kernel_launch(void* const* d_in, const int* in_sizes, int n_in,
                              void* d_out, int out_size, void* d_ws, size_t ws_size,
                              hipStream_t stream) {
    const float* feat0 = (const float*)d_in[0];
    const float* feat1 = (const float*)d_in[1];
    const float* feat2 = (const float*)d_in[2];
    const int*   src   = (const int*)d_in[3];
    const int*   dst   = (const int*)d_in[4];
    const float* W1_0  = (const float*)d_in[5];
    const float* b1_0  = (const float*)d_in[6];
    const float* W1_1  = (const float*)d_in[7];
    const float* b1_1  = (const float*)d_in[8];
    const float* W1_2  = (const float*)d_in[9];
    const float* b1_2  = (const float*)d_in[10];
    const float* al    = (const float*)d_in[11];
    const float* ar    = (const float*)d_in[12];
    const float* W2    = (const float*)d_in[13];
    const float* b2    = (const float*)d_in[14];
    const float* W3    = (const float*)d_in[15];
    const float* b3    = (const float*)d_in[16];

    float* out_logits  = (float*)d_out;
    float* out_encoded = (float*)d_out + (size_t)N_NODES * CLS;

    char* ws = (char*)d_ws;
    size_t off = 0;
    auto alloc = [&](size_t bytes) {
        void* p = ws + off;
        off = (off + bytes + 255) & ~(size_t)255;
        return p;
    };
    int*   row_ptr = (int*)alloc((N_NODES + 1) * sizeof(int));
    int*   deg     = (int*)alloc(N_NODES * sizeof(int));
    int*   tops    = (int*)alloc(64 * sizeof(int));
    int*   col     = (int*)alloc((size_t)N_EDGES * sizeof(int));
    float* h       = (float*)alloc((size_t)N_NODES * 64 * sizeof(float));
    float* s_h     = (float*)alloc(N_NODES * sizeof(float));
    float* x1      = (float*)alloc((size_t)HEADS * N_NODES * 64 * sizeof(float));
    float* s1      = (float*)alloc((size_t)HEADS * N_NODES * sizeof(float));
    (void)ws_size; (void)in_sizes; (void)n_in; (void)out_size;

    // CSR by dst
    hipMemsetAsync(deg, 0, N_NODES * sizeof(int), stream);
    hist_kernel<<<(N_EDGES + 255) / 256, 256, 0, stream>>>(dst, deg);
    int nb = (N_NODES + SCAN_B - 1) / SCAN_B;
    scan1_kernel<<<nb, SCAN_B, 0, stream>>>(deg, row_ptr, tops);
    scan2_kernel<<<1, 64, 0, stream>>>(tops, nb);
    scan3_kernel<<<nb, SCAN_B, 0, stream>>>(row_ptr, tops);
    hipMemsetAsync(deg, 0, N_NODES * sizeof(int), stream);
    scatter_kernel<<<(N_EDGES + 255) / 256, 256, 0, stream>>>(src, dst, row_ptr, deg, col);

    // projections
    proj_kernel<<<(20000 + 3) / 4, 256, 0, stream>>>(feat0, W1_0, b1_0, h, s_h, 20000, 256, 0);
    proj_kernel<<<(15000 + 3) / 4, 256, 0, stream>>>(feat1, W1_1, b1_1, h, s_h, 15000, 128, 20000);
    proj_kernel<<<(15000 + 3) / 4, 256, 0, stream>>>(feat2, W1_2, b1_2, h, s_h, 15000, 64, 35000);

    // convs + epilogue
    conv0_kernel<<<(N_NODES + 3) / 4, 256, 0, stream>>>(h, s_h, al, ar, row_ptr, col, x1, s1);
    conv1_fused_kernel<<<(N_NODES + 3) / 4, 256, 0, stream>>>(h, x1, s1, al, ar, row_ptr, col,
                                                              W2, b2, W3, b3,
                                                              out_logits, out_encoded);
}

// Round 3
// 523.000 us; speedup vs baseline: 1.1173x; 1.1173x over previous
//
#include <hip/hip_runtime.h>
#include <hip/hip_bf16.h>
#include <cmath>

#define N_NODES 50000
#define N_EDGES 800000
#define HID 64
#define HEADS 4
#define CONVS 2
#define CLS 16
#define SLOPE 0.2f
#define SCAN_B 1024
#define LOG2E 1.4426950408889634f

typedef unsigned int  uint32;
typedef unsigned short ushort16;

__device__ __forceinline__ ushort16 f2bf(float x) {
    union { float f; uint32 u; } v; v.f = x;
    uint32 r = v.u + 0x7fffu + ((v.u >> 16) & 1u);   // RNE
    return (ushort16)(r >> 16);
}
__device__ __forceinline__ float bf_lo(uint32 w) { return __uint_as_float(w << 16); }
__device__ __forceinline__ float bf_hi(uint32 w) { return __uint_as_float(w & 0xffff0000u); }

// ---------------- CSR build ----------------

__global__ void hist_kernel(const int* __restrict__ dst, int* __restrict__ deg) {
    int e = blockIdx.x * blockDim.x + threadIdx.x;
    if (e < N_EDGES) atomicAdd(&deg[dst[e]], 1);
}

__global__ void scan1_kernel(const int* __restrict__ deg, int* __restrict__ row_ptr,
                             int* __restrict__ tops) {
    __shared__ int buf[SCAN_B];
    int i = blockIdx.x * SCAN_B + threadIdx.x;
    int v = (i < N_NODES) ? deg[i] : 0;
    buf[threadIdx.x] = v;
    __syncthreads();
    for (int off = 1; off < SCAN_B; off <<= 1) {
        int t = (threadIdx.x >= off) ? buf[threadIdx.x - off] : 0;
        __syncthreads();
        buf[threadIdx.x] += t;
        __syncthreads();
    }
    if (i < N_NODES) row_ptr[i + 1] = buf[threadIdx.x];
    if (threadIdx.x == SCAN_B - 1) tops[blockIdx.x] = buf[threadIdx.x];
}

__global__ void scan2_kernel(int* __restrict__ tops, int nb) {
    if (threadIdx.x == 0 && blockIdx.x == 0) {
        int acc = 0;
        for (int b = 0; b < nb; b++) { int t = tops[b]; tops[b] = acc; acc += t; }
    }
}

__global__ void scan3_kernel(int* __restrict__ row_ptr, const int* __restrict__ tops) {
    int i = blockIdx.x * SCAN_B + threadIdx.x;
    if (i < N_NODES) row_ptr[i + 1] += tops[blockIdx.x];
    if (i == 0 && blockIdx.x == 0) row_ptr[0] = 0;
}

__global__ void scatter_kernel(const int* __restrict__ src, const int* __restrict__ dst,
                               const int* __restrict__ row_ptr, int* __restrict__ cursor,
                               int* __restrict__ col) {
    int e = blockIdx.x * blockDim.x + threadIdx.x;
    if (e < N_EDGES) {
        int d = dst[e];
        int pos = row_ptr[d] + atomicAdd(&cursor[d], 1);
        col[pos] = src[e];
    }
}

// ---------------- per-type projection: h = feat @ W1 + b1 (+ bf16 copy, rowsum) --------

__global__ __launch_bounds__(256)
void proj_kernel(const float* __restrict__ feat, const float* __restrict__ W,
                 const float* __restrict__ b, float* __restrict__ h,
                 ushort16* __restrict__ hb, float* __restrict__ s_out,
                 int rows, int K, int base_row) {
    int lane = threadIdx.x & 63;
    int wid  = threadIdx.x >> 6;
    int r = blockIdx.x * 4 + wid;
    if (r >= rows) return;
    const float* arow = feat + (size_t)r * K;
    float acc = b[lane];
    for (int kk = 0; kk < K; kk += 4) {
        float4 a4 = *reinterpret_cast<const float4*>(arow + kk);
        acc = fmaf(a4.x, W[(kk + 0) * 64 + lane], acc);
        acc = fmaf(a4.y, W[(kk + 1) * 64 + lane], acc);
        acc = fmaf(a4.z, W[(kk + 2) * 64 + lane], acc);
        acc = fmaf(a4.w, W[(kk + 3) * 64 + lane], acc);
    }
    int gr = base_row + r;
    h[(size_t)gr * 64 + lane]  = acc;
    hb[(size_t)gr * 64 + lane] = f2bf(acc);
    float ssum = acc;
    #pragma unroll
    for (int off = 32; off; off >>= 1) ssum += __shfl_xor(ssum, off);
    if (lane == 0) s_out[gr] = ssum;
}

// ---------------- conv 0 (4 heads fused; shared bf16 input gather) ----------------
// wave per dst node; lane = channel. logits scaled by log2e -> exp2.

__global__ __launch_bounds__(256)
void conv0_kernel(const ushort16* __restrict__ hb, const float* __restrict__ s_h,
                  const float* __restrict__ al, const float* __restrict__ ar,
                  const int* __restrict__ row_ptr, const int* __restrict__ col,
                  ushort16* __restrict__ x1p, float4* __restrict__ s1p) {
    int lane = threadIdx.x & 63;
    int wid  = threadIdx.x >> 6;
    int n = blockIdx.x * 4 + wid;
    if (n >= N_NODES) return;

    float sd = s_h[n];
    int base = row_ptr[n];
    int deg  = row_ptr[n + 1] - base;

    float alk[HEADS], ck[HEADS], mm[HEADS], den[HEADS], num[HEADS];
    #pragma unroll
    for (int hd = 0; hd < HEADS; hd++) {
        alk[hd] = al[(hd * CONVS + 0) * 64 + lane] * LOG2E;
        ck[hd]  = ar[(hd * CONVS + 0) * 64 + lane] * LOG2E * sd;
    }

    // pass A: min/max of neighbor scalars (lane-parallel)
    float smax = -INFINITY, smin = INFINITY;
    for (int j = lane; j < deg; j += 64) {
        float sv = s_h[col[base + j]];
        smax = fmaxf(smax, sv);
        smin = fminf(smin, sv);
    }
    #pragma unroll
    for (int off = 32; off; off >>= 1) {
        smax = fmaxf(smax, __shfl_xor(smax, off));
        smin = fminf(smin, __shfl_xor(smin, off));
    }
    #pragma unroll
    for (int hd = 0; hd < HEADS; hd++) {
        float t1 = fmaf(alk[hd], smax, ck[hd]); t1 = fmaxf(t1, SLOPE * t1);
        float t2 = fmaf(alk[hd], smin, ck[hd]); t2 = fmaxf(t2, SLOPE * t2);
        mm[hd] = fmaxf(t1, t2);
        den[hd] = 0.f; num[hd] = 0.f;
    }

    // pass B: weighted aggregation, 1-edge prefetch
    int cj = col[base];
    float sv = s_h[cj];
    ushort16 hv = hb[(size_t)cj * 64 + lane];
    for (int j = 0; j < deg; j++) {
        int jn = (j + 1 < deg) ? j + 1 : j;
        int cn = col[base + jn];
        float sn = s_h[cn];
        ushort16 hn = hb[(size_t)cn * 64 + lane];
        float hf = __uint_as_float(((uint32)hv) << 16);
        #pragma unroll
        for (int hd = 0; hd < HEADS; hd++) {
            float t = fmaf(alk[hd], sv, ck[hd]);
            t = fmaxf(t, SLOPE * t);
            float w = exp2f(t - mm[hd]);
            den[hd] += w;
            num[hd] = fmaf(hf, w, num[hd]);
        }
        sv = sn; hv = hn;
    }

    float o[HEADS];
    #pragma unroll
    for (int hd = 0; hd < HEADS; hd++) o[hd] = num[hd] / den[hd];

    uint32 lo = ((uint32)f2bf(o[0])) | (((uint32)f2bf(o[1])) << 16);
    uint32 hi = ((uint32)f2bf(o[2])) | (((uint32)f2bf(o[3])) << 16);
    *reinterpret_cast<uint2*>(x1p + ((size_t)n * 64 + lane) * 4) = make_uint2(lo, hi);

    float s0 = o[0], s1v = o[1], s2 = o[2], s3 = o[3];
    #pragma unroll
    for (int off = 32; off; off >>= 1) {
        s0 += __shfl_xor(s0, off); s1v += __shfl_xor(s1v, off);
        s2 += __shfl_xor(s2, off); s3  += __shfl_xor(s3, off);
    }
    if (lane == 0) s1p[n] = make_float4(s0, s1v, s2, s3);
}

// ---------------- conv 1 + residual + relu + z@W2+b2 + relu@W3+b3 ----------------

__global__ __launch_bounds__(256)
void conv1_fused_kernel(const float* __restrict__ h, const ushort16* __restrict__ x1p,
                        const float4* __restrict__ s1p,
                        const float* __restrict__ al, const float* __restrict__ ar,
                        const int* __restrict__ row_ptr, const int* __restrict__ col,
                        const float* __restrict__ W2, const float* __restrict__ b2,
                        const float* __restrict__ W3, const float* __restrict__ b3,
                        float* __restrict__ out_logits, float* __restrict__ out_encoded) {
    int lane = threadIdx.x & 63;
    int wid  = threadIdx.x >> 6;
    int n = blockIdx.x * 4 + wid;
    if (n >= N_NODES) return;

    int base = row_ptr[n];
    int deg  = row_ptr[n + 1] - base;

    float4 sdn = s1p[n];
    float sdv[HEADS] = {sdn.x, sdn.y, sdn.z, sdn.w};
    float alk[HEADS], ck[HEADS], mm[HEADS], den[HEADS], num[HEADS];
    #pragma unroll
    for (int hd = 0; hd < HEADS; hd++) {
        alk[hd] = al[(hd * CONVS + 1) * 64 + lane] * LOG2E;
        ck[hd]  = ar[(hd * CONVS + 1) * 64 + lane] * LOG2E * sdv[hd];
    }

    float smax0 = -INFINITY, smin0 = INFINITY, smax1 = -INFINITY, smin1 = INFINITY;
    float smax2 = -INFINITY, smin2 = INFINITY, smax3 = -INFINITY, smin3 = INFINITY;
    for (int j = lane; j < deg; j += 64) {
        float4 v = s1p[col[base + j]];
        smax0 = fmaxf(smax0, v.x); smin0 = fminf(smin0, v.x);
        smax1 = fmaxf(smax1, v.y); smin1 = fminf(smin1, v.y);
        smax2 = fmaxf(smax2, v.z); smin2 = fminf(smin2, v.z);
        smax3 = fmaxf(smax3, v.w); smin3 = fminf(smin3, v.w);
    }
    #pragma unroll
    for (int off = 32; off; off >>= 1) {
        smax0 = fmaxf(smax0, __shfl_xor(smax0, off)); smin0 = fminf(smin0, __shfl_xor(smin0, off));
        smax1 = fmaxf(smax1, __shfl_xor(smax1, off)); smin1 = fminf(smin1, __shfl_xor(smin1, off));
        smax2 = fmaxf(smax2, __shfl_xor(smax2, off)); smin2 = fminf(smin2, __shfl_xor(smin2, off));
        smax3 = fmaxf(smax3, __shfl_xor(smax3, off)); smin3 = fminf(smin3, __shfl_xor(smin3, off));
    }
    {
        float smaxA[HEADS] = {smax0, smax1, smax2, smax3};
        float sminA[HEADS] = {smin0, smin1, smin2, smin3};
        #pragma unroll
        for (int hd = 0; hd < HEADS; hd++) {
            float t1 = fmaf(alk[hd], smaxA[hd], ck[hd]); t1 = fmaxf(t1, SLOPE * t1);
            float t2 = fmaf(alk[hd], sminA[hd], ck[hd]); t2 = fmaxf(t2, SLOPE * t2);
            mm[hd] = fmaxf(t1, t2);
            den[hd] = 0.f; num[hd] = 0.f;
        }
    }

    // main loop: per edge 3 loads (col, s1p float4 broadcast, x1p 8B gather)
    int cj = col[base];
    float4 sv4 = s1p[cj];
    uint2 xv = *reinterpret_cast<const uint2*>(x1p + ((size_t)cj * 64 + lane) * 4);
    for (int j = 0; j < deg; j++) {
        int jn = (j + 1 < deg) ? j + 1 : j;
        int cn = col[base + jn];
        float4 sn4 = s1p[cn];
        uint2 xn = *reinterpret_cast<const uint2*>(x1p + ((size_t)cn * 64 + lane) * 4);
        float xf[HEADS] = {bf_lo(xv.x), bf_hi(xv.x), bf_lo(xv.y), bf_hi(xv.y)};
        float sf[HEADS] = {sv4.x, sv4.y, sv4.z, sv4.w};
        #pragma unroll
        for (int hd = 0; hd < HEADS; hd++) {
            float t = fmaf(alk[hd], sf[hd], ck[hd]);
            t = fmaxf(t, SLOPE * t);
            float w = exp2f(t - mm[hd]);
            den[hd] += w;
            num[hd] = fmaf(xf[hd], w, num[hd]);
        }
        sv4 = sn4; xv = xn;
    }

    float hres = h[(size_t)n * 64 + lane];
    float z0 = fmaxf(hres + num[0] / den[0], 0.f);
    float z1 = fmaxf(hres + num[1] / den[1], 0.f);
    float z2 = fmaxf(hres + num[2] / den[2], 0.f);
    float z3 = fmaxf(hres + num[3] / den[3], 0.f);

    // encoded[n, lane] = sum_kk z[kk] * W2[kk, lane] + b2[lane]
    float acc = b2[lane];
    const float* w2p = W2 + lane;
    #pragma unroll 4
    for (int q = 0; q < 64; q++) { float zv = __shfl(z0, q); acc = fmaf(zv, w2p[(0 * 64 + q) * 64], acc); }
    #pragma unroll 4
    for (int q = 0; q < 64; q++) { float zv = __shfl(z1, q); acc = fmaf(zv, w2p[(1 * 64 + q) * 64], acc); }
    #pragma unroll 4
    for (int q = 0; q < 64; q++) { float zv = __shfl(z2, q); acc = fmaf(zv, w2p[(2 * 64 + q) * 64], acc); }
    #pragma unroll 4
    for (int q = 0; q < 64; q++) { float zv = __shfl(z3, q); acc = fmaf(zv, w2p[(3 * 64 + q) * 64], acc); }
    out_encoded[(size_t)n * 64 + lane] = acc;

    // logits[n, c] = sum_k relu(enc_k) * W3[k, c] + b3[c]
    float er = fmaxf(acc, 0.f);
    int c16 = lane & 15;
    int k0  = (lane >> 4) * 16;
    float part = 0.f;
    #pragma unroll
    for (int j = 0; j < 16; j++) {
        float ev = __shfl(er, k0 + j);
        part = fmaf(ev, W3[(k0 + j) * CLS + c16], part);
    }
    part += __shfl_xor(part, 16);
    part += __shfl_xor(part, 32);
    if (lane < CLS) out_logits[(size_t)n * CLS + lane] = part + b3[lane];
}

// ---------------- launch ----------------

extern "C" void kernel_launch(void* const* d_in, const int* in_sizes, int n_in,
                              void* d_out, int out_size, void* d_ws, size_t ws_size,
                              hipStream_t stream) {
    const float* feat0 = (const float*)d_in[0];
    const float* feat1 = (const float*)d_in[1];
    const float* feat2 = (const float*)d_in[2];
    const int*   src   = (const int*)d_in[3];
    const int*   dst   = (const int*)d_in[4];
    const float* W1_0  = (const float*)d_in[5];
    const float* b1_0  = (const float*)d_in[6];
    const float* W1_1  = (const float*)d_in[7];
    const float* b1_1  = (const float*)d_in[8];
    const float* W1_2  = (const float*)d_in[9];
    const float* b1_2  = (const float*)d_in[10];
    const float* al    = (const float*)d_in[11];
    const float* ar    = (const float*)d_in[12];
    const float* W2    = (const float*)d_in[13];
    const float* b2    = (const float*)d_in[14];
    const float* W3    = (const float*)d_in[15];
    const float* b3    = (const float*)d_in[16];

    float* out_logits  = (float*)d_out;
    float* out_encoded = (float*)d_out + (size_t)N_NODES * CLS;

    char* ws = (char*)d_ws;
    size_t off = 0;
    auto alloc = [&](size_t bytes) {
        void* p = ws + off;
        off = (off + bytes + 255) & ~(size_t)255;
        return p;
    };
    int*      row_ptr = (int*)alloc((N_NODES + 1) * sizeof(int));
    int*      deg     = (int*)alloc(N_NODES * sizeof(int));
    int*      tops    = (int*)alloc(64 * sizeof(int));
    int*      col     = (int*)alloc((size_t)N_EDGES * sizeof(int));
    float*    h       = (float*)alloc((size_t)N_NODES * 64 * sizeof(float));
    ushort16* hb      = (ushort16*)alloc((size_t)N_NODES * 64 * sizeof(ushort16));
    float*    s_h     = (float*)alloc(N_NODES * sizeof(float));
    ushort16* x1p     = (ushort16*)alloc((size_t)N_NODES * 64 * 4 * sizeof(ushort16));
    float4*   s1p     = (float4*)alloc(N_NODES * sizeof(float4));
    (void)ws_size; (void)in_sizes; (void)n_in; (void)out_size;

    // CSR by dst
    (void)hipMemsetAsync(deg, 0, N_NODES * sizeof(int), stream);
    hist_kernel<<<(N_EDGES + 255) / 256, 256, 0, stream>>>(dst, deg);
    int nb = (N_NODES + SCAN_B - 1) / SCAN_B;
    scan1_kernel<<<nb, SCAN_B, 0, stream>>>(deg, row_ptr, tops);
    scan2_kernel<<<1, 64, 0, stream>>>(tops, nb);
    scan3_kernel<<<nb, SCAN_B, 0, stream>>>(row_ptr, tops);
    (void)hipMemsetAsync(deg, 0, N_NODES * sizeof(int), stream);
    scatter_kernel<<<(N_EDGES + 255) / 256, 256, 0, stream>>>(src, dst, row_ptr, deg, col);

    // projections
    proj_kernel<<<(20000 + 3) / 4, 256, 0, stream>>>(feat0, W1_0, b1_0, h, hb, s_h, 20000, 256, 0);
    proj_kernel<<<(15000 + 3) / 4, 256, 0, stream>>>(feat1, W1_1, b1_1, h, hb, s_h, 15000, 128, 20000);
    proj_kernel<<<(15000 + 3) / 4, 256, 0, stream>>>(feat2, W1_2, b1_2, h, hb, s_h, 15000, 64, 35000);

    // convs + epilogue
    conv0_kernel<<<(N_NODES + 3) / 4, 256, 0, stream>>>(hb, s_h, al, ar, row_ptr, col, x1p, s1p);
    conv1_fused_kernel<<<(N_NODES + 3) / 4, 256, 0, stream>>>(h, x1p, s1p, al, ar, row_ptr, col,
                                                              W2, b2, W3, b3,
                                                              out_logits, out_encoded);
}